// Round 1
// baseline (295.592 us; speedup 1.0000x reference)
//
#include <hip/hip_runtime.h>

typedef __bf16 bf16;
typedef __bf16 bf16x8 __attribute__((ext_vector_type(8)));
typedef __bf16 bf16x4 __attribute__((ext_vector_type(4)));
typedef float  f32x4  __attribute__((ext_vector_type(4)));

#define AS1 __attribute__((address_space(1)))
#define AS3 __attribute__((address_space(3)))

__device__ __forceinline__ void gload16(void* g, void* l) {
  // 16B-wide async global->LDS. LDS dest must be linear (wave-uniform base + lane*16).
  __builtin_amdgcn_global_load_lds((AS1 void*)g, (AS3 void*)l, 16, 0, 0);
}

// ---------------- cast fp32 -> bf16 (vectorized) ----------------
__global__ void cast_bf16_k(const float4* __restrict__ in, bf16x4* __restrict__ out, int n4) {
  int i = blockIdx.x * 256 + threadIdx.x;
  if (i < n4) {
    float4 v = in[i];
    bf16x4 o;
    o[0] = (bf16)v.x; o[1] = (bf16)v.y; o[2] = (bf16)v.z; o[3] = (bf16)v.w;
    out[i] = o;
  }
}

// ---------------- GEMM: C[M,N] = A[M,K] * Bt[N,K]^T, bf16 in, fp32 out ----------
// 128x128 tile, BK=32, 4 waves (2x2), each wave 64x64 via 4x4 16x16x32 MFMA frags.
// LDS staged via global_load_lds with source-side XOR swizzle (slot ^= (row>>1)&3)
// so the strided ds_read_b128 fragment reads are only 2-way conflicted (free).
__global__ __launch_bounds__(256) void gemm_bt(const bf16* __restrict__ A,
                                               const bf16* __restrict__ Bt,
                                               float* __restrict__ C,
                                               int M, int N, int K) {
  __shared__ __align__(16) char As[8192];
  __shared__ __align__(16) char Bs[8192];
  const int t = threadIdx.x;
  const int w = t >> 6, l = t & 63, lr = l & 15, lh = l >> 4;
  const int m0 = blockIdx.y << 7, n0 = blockIdx.x << 7;
  const int wr = w >> 1, wc = w & 1;

  f32x4 acc[4][4];
#pragma unroll
  for (int i = 0; i < 4; i++)
#pragma unroll
    for (int j = 0; j < 4; j++) acc[i][j] = {0.f, 0.f, 0.f, 0.f};

  const int nk = K >> 5;
  for (int kt = 0; kt < nk; kt++) {
    __syncthreads();  // protect previous tile reads
#pragma unroll
    for (int pass = 0; pass < 2; pass++) {
      int c = t + (pass << 8);          // 512 chunks of 16B per 8KB tile
      int row = c >> 2, slot = c & 3;
      int gs = slot ^ ((row >> 1) & 3); // inverse swizzle on the global source
      gload16((void*)(A  + (long)(m0 + row) * K + (kt << 5) + (gs << 3)), As + c * 16);
      gload16((void*)(Bt + (long)(n0 + row) * K + (kt << 5) + (gs << 3)), Bs + c * 16);
    }
    __syncthreads();  // drains vmcnt before compute

    bf16x8 af[4], bfr[4];
#pragma unroll
    for (int mi = 0; mi < 4; mi++) {
      int row = (wr << 6) + (mi << 4) + lr;
      af[mi] = *(const bf16x8*)(As + row * 64 + ((lh << 4) ^ (((row >> 1) & 3) << 4)));
    }
#pragma unroll
    for (int ni = 0; ni < 4; ni++) {
      int row = (wc << 6) + (ni << 4) + lr;
      bfr[ni] = *(const bf16x8*)(Bs + row * 64 + ((lh << 4) ^ (((row >> 1) & 3) << 4)));
    }
#pragma unroll
    for (int mi = 0; mi < 4; mi++)
#pragma unroll
      for (int ni = 0; ni < 4; ni++)
        acc[mi][ni] = __builtin_amdgcn_mfma_f32_16x16x32_bf16(af[mi], bfr[ni], acc[mi][ni], 0, 0, 0);
  }

#pragma unroll
  for (int mi = 0; mi < 4; mi++)
#pragma unroll
    for (int ni = 0; ni < 4; ni++) {
      int col  = n0 + (wc << 6) + (ni << 4) + lr;
      int rowb = m0 + (wr << 6) + (mi << 4) + (lh << 2);
#pragma unroll
      for (int r = 0; r < 4; r++)
        C[(long)(rowb + r) * N + col] = acc[mi][ni][r];
    }
}

// ---------------- RoPE + pack + KV-cache write -------------------
// qf: [4096][2048] fp32 ; kvf: [4096][1024] fp32 (k cols 0..511, v cols 512..1023)
__global__ void rope_pack(const float* __restrict__ qf, const float* __restrict__ kvf,
                          const float* __restrict__ fc, const float* __restrict__ fs,
                          bf16* __restrict__ qb, bf16* __restrict__ kbf,
                          float* __restrict__ kcache, float* __restrict__ vcache) {
  const int bs = blockIdx.x, s = bs & 1023, t = threadIdx.x;
  const float qscale = 0.08838834764831845f;  // 1/sqrt(128), folded into Q
#pragma unroll
  for (int p = t; p < 1024; p += 256) {       // q: 1024 rotation pairs
    int h = p >> 6, i = p & 63;
    long base = ((long)bs << 11) + (h << 7) + (i << 1);
    float c = fc[(s << 6) + i], sn = fs[(s << 6) + i];
    float xr = qf[base], xi = qf[base + 1];
    qb[base]     = (bf16)((xr * c - xi * sn) * qscale);
    qb[base + 1] = (bf16)((xr * sn + xi * c) * qscale);
  }
  {                                           // k: 256 rotation pairs
    int kvh = t >> 6, i = t & 63;
    long src = ((long)bs << 10) + (kvh << 7) + (i << 1);
    long dst = ((long)bs << 9)  + (kvh << 7) + (i << 1);
    float c = fc[(s << 6) + i], sn = fs[(s << 6) + i];
    float xr = kvf[src], xi = kvf[src + 1];
    float vr = xr * c - xi * sn, vi = xr * sn + xi * c;
    kbf[dst] = (bf16)vr; kbf[dst + 1] = (bf16)vi;
    kcache[dst] = vr; kcache[dst + 1] = vi;
  }
  {                                           // v cache copy (fp32)
    long srcb = ((long)bs << 10) + 512;
    long dstb = ((long)bs << 9);
    vcache[dstb + t]       = kvf[srcb + t];
    vcache[dstb + 256 + t] = kvf[srcb + 256 + t];
  }
}

// ---------------- V transpose: [b][s][kv][hd] fp32 -> vt bf16 [b*4+kv][hd][s] ----
__global__ void vtrans(const float* __restrict__ kvf, bf16* __restrict__ vt) {
  const int bkv = blockIdx.x, s0 = blockIdx.y << 6;
  const int b = bkv >> 2, kvh = bkv & 3;
  __shared__ bf16 tile[128][66];
  const int t = threadIdx.x;
  for (int idx = t; idx < 8192; idx += 256) {
    int r = idx >> 7, hd = idx & 127;
    tile[hd][r] = (bf16)kvf[((long)(b * 1024 + s0 + r) << 10) + 512 + (kvh << 7) + hd];
  }
  __syncthreads();
  for (int j = t; j < 8192; j += 256) {
    int hd = j >> 6, col = j & 63;
    vt[((long)(bkv << 7) + hd) * 1024 + s0 + col] = tile[hd][col];
  }
}

// ---------------- Flash attention (causal, GQA) -------------------
// block = 4 waves; each wave owns 16 q-rows of a 64-row q-tile. KVBLK=64.
// K tile [64][128] and Vt tile [128][64] staged with XOR swizzle (byte ^= (row&7)<<4).
__global__ __launch_bounds__(256) void attn_k(const bf16* __restrict__ qb,
                                              const bf16* __restrict__ kb,
                                              const bf16* __restrict__ vt,
                                              bf16* __restrict__ aob) {
  const int qt = blockIdx.x;            // q tile (16)
  const int bh = blockIdx.y;            // b*16 + h (64)
  const int b = bh >> 4, h = bh & 15, kv = h >> 2;
  const int t = threadIdx.x, w = t >> 6, l = t & 63, lr = l & 15, lh = l >> 4;
  __shared__ __align__(16) char Ks[16384];
  __shared__ __align__(16) char Vs[16384];
  __shared__ __align__(16) bf16 Ps[4][16][72];   // per-wave P, padded: stride 144B (9x16B)

  bf16x8 qfrag[4];
  {
    const int qrow = (qt << 6) + (w << 4) + lr;
    const bf16* qp = qb + ((long)(b * 1024 + qrow) << 11) + (h << 7);
#pragma unroll
    for (int kc = 0; kc < 4; kc++) qfrag[kc] = *(const bf16x8*)(qp + (kc << 5) + (lh << 3));
  }

  f32x4 acc[8];
#pragma unroll
  for (int i = 0; i < 8; i++) acc[i] = {0.f, 0.f, 0.f, 0.f};
  float m[4]  = {-1e30f, -1e30f, -1e30f, -1e30f};
  float ls[4] = {0.f, 0.f, 0.f, 0.f};

  const bf16* kg = kb + ((long)b << 19) + (kv << 7);     // [b][s][kv*128+..], row stride 512
  const bf16* vg = vt + ((long)(b * 4 + kv) << 17);      // [bkv][hd][s], row stride 1024
  const int nt = qt + 1;                                 // causal: only tiles <= qt

  for (int tt = 0; tt < nt; tt++) {
    const int kv0 = tt << 6;
#pragma unroll
    for (int pass = 0; pass < 4; pass++) {
      int c = t + (pass << 8);
      { int row = c >> 4, slot = c & 15, gs = slot ^ (row & 7);
        gload16((void*)(kg + (long)(kv0 + row) * 512 + (gs << 3)), Ks + c * 16); }
      { int row = c >> 3, slot = c & 7,  gs = slot ^ (row & 7);
        gload16((void*)(vg + (long)row * 1024 + kv0 + (gs << 3)), Vs + c * 16); }
    }
    __syncthreads();

    // S = Q @ K^T (scale pre-folded into Q)
    f32x4 s4[4];
#pragma unroll
    for (int nf = 0; nf < 4; nf++) s4[nf] = {0.f, 0.f, 0.f, 0.f};
#pragma unroll
    for (int nf = 0; nf < 4; nf++) {
      int key = (nf << 4) + lr;
#pragma unroll
      for (int kc = 0; kc < 4; kc++) {
        bf16x8 kf8 = *(const bf16x8*)(Ks + key * 256 + (((kc << 6) + (lh << 4)) ^ ((key & 7) << 4)));
        s4[nf] = __builtin_amdgcn_mfma_f32_16x16x32_bf16(qfrag[kc], kf8, s4[nf], 0, 0, 0);
      }
    }
    if (tt == qt) {  // causal mask only needed on the diagonal tile
#pragma unroll
      for (int nf = 0; nf < 4; nf++) {
        int key = kv0 + (nf << 4) + lr;
#pragma unroll
        for (int r = 0; r < 4; r++) {
          int qg = (qt << 6) + (w << 4) + (lh << 2) + r;
          if (key > qg) s4[nf][r] = -1e30f;
        }
      }
    }

    // online softmax (rows live across a 16-lane group; reduce via shfl_xor)
    float mc[4];
#pragma unroll
    for (int r = 0; r < 4; r++)
      mc[r] = fmaxf(fmaxf(s4[0][r], s4[1][r]), fmaxf(s4[2][r], s4[3][r]));
#pragma unroll
    for (int d = 1; d < 16; d <<= 1)
#pragma unroll
      for (int r = 0; r < 4; r++) mc[r] = fmaxf(mc[r], __shfl_xor(mc[r], d));
    float al[4];
#pragma unroll
    for (int r = 0; r < 4; r++) {
      float mn = fmaxf(m[r], mc[r]);
      al[r] = __expf(m[r] - mn);
      m[r] = mn;
    }
    float rs[4] = {0.f, 0.f, 0.f, 0.f};
#pragma unroll
    for (int nf = 0; nf < 4; nf++)
#pragma unroll
      for (int r = 0; r < 4; r++) {
        float p = __expf(s4[nf][r] - m[r]);
        s4[nf][r] = p;
        rs[r] += p;
      }
#pragma unroll
    for (int d = 1; d < 16; d <<= 1)
#pragma unroll
      for (int r = 0; r < 4; r++) rs[r] += __shfl_xor(rs[r], d);
    f32x4 av = {al[0], al[1], al[2], al[3]};
#pragma unroll
    for (int r = 0; r < 4; r++) ls[r] = ls[r] * al[r] + rs[r];
#pragma unroll
    for (int hf = 0; hf < 8; hf++) acc[hf] *= av;

    // P -> LDS (per-wave region; layout transpose for the PV A-operand)
#pragma unroll
    for (int nf = 0; nf < 4; nf++)
#pragma unroll
      for (int r = 0; r < 4; r++)
        Ps[w][(lh << 2) + r][(nf << 4) + lr] = (bf16)s4[nf][r];

    // O += P @ V
#pragma unroll
    for (int kc = 0; kc < 2; kc++) {
      bf16x8 pf8 = *(const bf16x8*)((const char*)&Ps[w][lr][0] + (kc << 6) + (lh << 4));
#pragma unroll
      for (int hf = 0; hf < 8; hf++) {
        int hd = (hf << 4) + lr;
        bf16x8 vf8 = *(const bf16x8*)(Vs + hd * 128 + (((kc << 6) + (lh << 4)) ^ ((hd & 7) << 4)));
        acc[hf] = __builtin_amdgcn_mfma_f32_16x16x32_bf16(pf8, vf8, acc[hf], 0, 0, 0);
      }
    }
    __syncthreads();  // protect K/V LDS before next stage
  }

  float inv[4];
#pragma unroll
  for (int r = 0; r < 4; r++) inv[r] = 1.f / ls[r];
#pragma unroll
  for (int hf = 0; hf < 8; hf++)
#pragma unroll
    for (int r = 0; r < 4; r++) {
      int qrow = (qt << 6) + (w << 4) + (lh << 2) + r;
      aob[((long)(b * 1024 + qrow) << 11) + (h << 7) + (hf << 4) + lr] = (bf16)(acc[hf][r] * inv[r]);
    }
}

// ---------------- launch -----------------------------------------
extern "C" void kernel_launch(void* const* d_in, const int* in_sizes, int n_in,
                              void* d_out, int out_size, void* d_ws, size_t ws_size,
                              hipStream_t stream) {
  (void)in_sizes; (void)n_in; (void)out_size; (void)ws_size;
  const float* x  = (const float*)d_in[0];
  const float* fc = (const float*)d_in[1];
  const float* fs = (const float*)d_in[2];
  // d_in[3] = attention_mask: pure causal, implemented directly.
  const float* wq = (const float*)d_in[4];
  const float* wk = (const float*)d_in[5];
  const float* wv = (const float*)d_in[6];
  const float* wo = (const float*)d_in[7];

  float* out    = (float*)d_out;
  float* kcache = out + 8388608;   // (4,1024,4,128)
  float* vcache = out + 10485760;  // (4,1024,4,128)

  char* ws = (char*)d_ws;
  bf16*  xb   = (bf16*)(ws);                    // 16 MB  x bf16
  bf16*  wqb  = (bf16*)(ws + 16777216);         // 8 MB
  bf16*  wkvb = (bf16*)(ws + 25165824);         // 4 MB  (wk rows then wv rows)
  bf16*  wob  = (bf16*)(ws + 29360128);         // 8 MB
  float* qf   = (float*)(ws + 37748736);        // 32 MB q fp32
  float* kvf  = (float*)(ws + 71303168);        // 16 MB kv fp32
  bf16*  qbb  = (bf16*)(ws + 88080384);         // 16 MB q bf16 (roped, scaled)
  bf16*  kbf  = (bf16*)(ws + 104857600);        // 4 MB  k bf16 (roped)
  bf16*  vtb  = (bf16*)(ws + 109051904);        // 4 MB  v^T bf16
  bf16*  aob  = (bf16*)(ws + 113246208);        // 16 MB attn out bf16
  // total ws use: ~124 MB

  cast_bf16_k<<<8192, 256, 0, stream>>>((const float4*)x,  (bf16x4*)xb,   2097152);
  cast_bf16_k<<<4096, 256, 0, stream>>>((const float4*)wq, (bf16x4*)wqb,  1048576);
  cast_bf16_k<<<1024, 256, 0, stream>>>((const float4*)wk, (bf16x4*)wkvb,  262144);
  cast_bf16_k<<<1024, 256, 0, stream>>>((const float4*)wv, (bf16x4*)(wkvb + 1048576), 262144);
  cast_bf16_k<<<4096, 256, 0, stream>>>((const float4*)wo, (bf16x4*)wob,  1048576);

  gemm_bt<<<dim3(16, 32), 256, 0, stream>>>(xb, wqb,  qf,  4096, 2048, 2048);
  gemm_bt<<<dim3(8, 32),  256, 0, stream>>>(xb, wkvb, kvf, 4096, 1024, 2048);

  rope_pack<<<4096, 256, 0, stream>>>(qf, kvf, fc, fs, qbb, kbf, kcache, vcache);
  vtrans<<<dim3(16, 16), 256, 0, stream>>>(kvf, vtb);

  attn_k<<<dim3(16, 64), 256, 0, stream>>>(qbb, kbf, vtb, aob);

  gemm_bt<<<dim3(16, 32), 256, 0, stream>>>(aob, wob, out, 4096, 2048, 2048);
}

// Round 2
// 235.147 us; speedup vs baseline: 1.2571x; 1.2571x over previous
//
#include <hip/hip_runtime.h>

typedef __bf16 bf16;
typedef __bf16 bf16x8 __attribute__((ext_vector_type(8)));
typedef __bf16 bf16x4 __attribute__((ext_vector_type(4)));
typedef float  f32x4  __attribute__((ext_vector_type(4)));

#define AS1 __attribute__((address_space(1)))
#define AS3 __attribute__((address_space(3)))

__device__ __forceinline__ void gload16(void* g, void* l) {
  // 16B-wide async global->LDS. LDS dest must be linear (wave-uniform base + lane*16).
  __builtin_amdgcn_global_load_lds((AS1 void*)g, (AS3 void*)l, 16, 0, 0);
}

// ---------------- fused cast fp32 -> bf16 for x + all weights ----------------
__global__ void cast_all(const float4* __restrict__ x,  const float4* __restrict__ wq,
                         const float4* __restrict__ wk, const float4* __restrict__ wv,
                         const float4* __restrict__ wo,
                         bf16x4* __restrict__ xb, bf16x4* __restrict__ wqb,
                         bf16x4* __restrict__ wkvb, bf16x4* __restrict__ wob) {
  long i = (long)blockIdx.x * 256 + threadIdx.x;
  float4 v; bf16x4* dp;
  if (i < 2097152)      { v = x[i];            dp = xb + i; }
  else if (i < 3145728) { v = wq[i - 2097152]; dp = wqb + (i - 2097152); }
  else if (i < 3407872) { v = wk[i - 3145728]; dp = wkvb + (i - 3145728); }
  else if (i < 3670016) { v = wv[i - 3407872]; dp = wkvb + 262144 + (i - 3407872); }
  else                  { v = wo[i - 3670016]; dp = wob + (i - 3670016); }
  bf16x4 o;
  o[0] = (bf16)v.x; o[1] = (bf16)v.y; o[2] = (bf16)v.z; o[3] = (bf16)v.w;
  *dp = o;
}

// ---------------- GEMM: C[M,N] = A[M,K] * Bt[N,K]^T, bf16 in, fp32 out ----------
__global__ __launch_bounds__(256) void gemm_bt(const bf16* __restrict__ A,
                                               const bf16* __restrict__ Bt,
                                               float* __restrict__ C,
                                               int M, int N, int K) {
  __shared__ __align__(16) char As[8192];
  __shared__ __align__(16) char Bs[8192];
  const int t = threadIdx.x;
  const int w = t >> 6, l = t & 63, lr = l & 15, lh = l >> 4;
  const int m0 = blockIdx.y << 7, n0 = blockIdx.x << 7;
  const int wr = w >> 1, wc = w & 1;

  f32x4 acc[4][4];
#pragma unroll
  for (int i = 0; i < 4; i++)
#pragma unroll
    for (int j = 0; j < 4; j++) acc[i][j] = {0.f, 0.f, 0.f, 0.f};

  const int nk = K >> 5;
  for (int kt = 0; kt < nk; kt++) {
    __syncthreads();
#pragma unroll
    for (int pass = 0; pass < 2; pass++) {
      int c = t + (pass << 8);
      int row = c >> 2, slot = c & 3;
      int gs = slot ^ ((row >> 1) & 3);
      gload16((void*)(A  + (long)(m0 + row) * K + (kt << 5) + (gs << 3)), As + c * 16);
      gload16((void*)(Bt + (long)(n0 + row) * K + (kt << 5) + (gs << 3)), Bs + c * 16);
    }
    __syncthreads();

    bf16x8 af[4], bfr[4];
#pragma unroll
    for (int mi = 0; mi < 4; mi++) {
      int row = (wr << 6) + (mi << 4) + lr;
      af[mi] = *(const bf16x8*)(As + row * 64 + ((lh << 4) ^ (((row >> 1) & 3) << 4)));
    }
#pragma unroll
    for (int ni = 0; ni < 4; ni++) {
      int row = (wc << 6) + (ni << 4) + lr;
      bfr[ni] = *(const bf16x8*)(Bs + row * 64 + ((lh << 4) ^ (((row >> 1) & 3) << 4)));
    }
    __builtin_amdgcn_s_setprio(1);
#pragma unroll
    for (int mi = 0; mi < 4; mi++)
#pragma unroll
      for (int ni = 0; ni < 4; ni++)
        acc[mi][ni] = __builtin_amdgcn_mfma_f32_16x16x32_bf16(af[mi], bfr[ni], acc[mi][ni], 0, 0, 0);
    __builtin_amdgcn_s_setprio(0);
  }

#pragma unroll
  for (int mi = 0; mi < 4; mi++)
#pragma unroll
    for (int ni = 0; ni < 4; ni++) {
      int col  = n0 + (wc << 6) + (ni << 4) + lr;
      int rowb = m0 + (wr << 6) + (mi << 4) + (lh << 2);
#pragma unroll
      for (int r = 0; r < 4; r++)
        C[(long)(rowb + r) * N + col] = acc[mi][ni][r];
    }
}

// ---------------- Q GEMM with fused RoPE + 1/sqrt(HD) scale, bf16 out ----------
// Identical mainloop to gemm_bt; epilogue rotates adjacent-column pairs via shfl_xor(1).
__global__ __launch_bounds__(256) void gemm_q(const bf16* __restrict__ A,
                                              const bf16* __restrict__ Bt,
                                              bf16* __restrict__ Qb,
                                              const float* __restrict__ fc,
                                              const float* __restrict__ fs,
                                              int M, int N, int K) {
  __shared__ __align__(16) char As[8192];
  __shared__ __align__(16) char Bs[8192];
  const int t = threadIdx.x;
  const int w = t >> 6, l = t & 63, lr = l & 15, lh = l >> 4;
  const int m0 = blockIdx.y << 7, n0 = blockIdx.x << 7;
  const int wr = w >> 1, wc = w & 1;

  f32x4 acc[4][4];
#pragma unroll
  for (int i = 0; i < 4; i++)
#pragma unroll
    for (int j = 0; j < 4; j++) acc[i][j] = {0.f, 0.f, 0.f, 0.f};

  const int nk = K >> 5;
  for (int kt = 0; kt < nk; kt++) {
    __syncthreads();
#pragma unroll
    for (int pass = 0; pass < 2; pass++) {
      int c = t + (pass << 8);
      int row = c >> 2, slot = c & 3;
      int gs = slot ^ ((row >> 1) & 3);
      gload16((void*)(A  + (long)(m0 + row) * K + (kt << 5) + (gs << 3)), As + c * 16);
      gload16((void*)(Bt + (long)(n0 + row) * K + (kt << 5) + (gs << 3)), Bs + c * 16);
    }
    __syncthreads();

    bf16x8 af[4], bfr[4];
#pragma unroll
    for (int mi = 0; mi < 4; mi++) {
      int row = (wr << 6) + (mi << 4) + lr;
      af[mi] = *(const bf16x8*)(As + row * 64 + ((lh << 4) ^ (((row >> 1) & 3) << 4)));
    }
#pragma unroll
    for (int ni = 0; ni < 4; ni++) {
      int row = (wc << 6) + (ni << 4) + lr;
      bfr[ni] = *(const bf16x8*)(Bs + row * 64 + ((lh << 4) ^ (((row >> 1) & 3) << 4)));
    }
    __builtin_amdgcn_s_setprio(1);
#pragma unroll
    for (int mi = 0; mi < 4; mi++)
#pragma unroll
      for (int ni = 0; ni < 4; ni++)
        acc[mi][ni] = __builtin_amdgcn_mfma_f32_16x16x32_bf16(af[mi], bfr[ni], acc[mi][ni], 0, 0, 0);
    __builtin_amdgcn_s_setprio(0);
  }

  const float qscale = 0.08838834764831845f;  // 1/sqrt(128)
  const int im = lr & 1;                       // odd column -> imaginary slot
#pragma unroll
  for (int mi = 0; mi < 4; mi++)
#pragma unroll
    for (int ni = 0; ni < 4; ni++) {
      int col  = n0 + (wc << 6) + (ni << 4) + lr;
      int i2   = (col & 127) >> 1;             // rotation index within head
      int rowb = m0 + (wr << 6) + (mi << 4) + (lh << 2);
#pragma unroll
      for (int r = 0; r < 4; r++) {
        int row = rowb + r, s = row & 1023;
        float c = fc[(s << 6) + i2], sn = fs[(s << 6) + i2];
        float own = acc[mi][ni][r];
        float oth = __shfl_xor(own, 1);
        float xr = im ? oth : own;
        float xi = im ? own : oth;
        float val = im ? (xr * sn + xi * c) : (xr * c - xi * sn);
        Qb[(long)row * N + col] = (bf16)(val * qscale);
      }
    }
}

// ---------------- RoPE for K + KV-cache writes (fp32) -------------------
__global__ void rope_pack_kv(const float* __restrict__ kvf,
                             const float* __restrict__ fc, const float* __restrict__ fs,
                             bf16* __restrict__ kbf,
                             float* __restrict__ kcache, float* __restrict__ vcache) {
  const int bs = blockIdx.x, s = bs & 1023, t = threadIdx.x;
  {                                           // k: 256 rotation pairs
    int kvh = t >> 6, i = t & 63;
    long src = ((long)bs << 10) + (kvh << 7) + (i << 1);
    long dst = ((long)bs << 9)  + (kvh << 7) + (i << 1);
    float c = fc[(s << 6) + i], sn = fs[(s << 6) + i];
    float xr = kvf[src], xi = kvf[src + 1];
    float vr = xr * c - xi * sn, vi = xr * sn + xi * c;
    kbf[dst] = (bf16)vr; kbf[dst + 1] = (bf16)vi;
    kcache[dst] = vr; kcache[dst + 1] = vi;
  }
  {                                           // v cache copy (fp32)
    long srcb = ((long)bs << 10) + 512;
    long dstb = ((long)bs << 9);
    vcache[dstb + t]       = kvf[srcb + t];
    vcache[dstb + 256 + t] = kvf[srcb + 256 + t];
  }
}

// ---------------- V transpose: [b][s][kv][hd] fp32 -> vt bf16 [b*4+kv][hd][s] ----
__global__ void vtrans(const float* __restrict__ kvf, bf16* __restrict__ vt) {
  const int bkv = blockIdx.x, s0 = blockIdx.y << 6;
  const int b = bkv >> 2, kvh = bkv & 3;
  __shared__ bf16 tile[128][66];
  const int t = threadIdx.x;
  for (int idx = t; idx < 8192; idx += 256) {
    int r = idx >> 7, hd = idx & 127;
    tile[hd][r] = (bf16)kvf[((long)(b * 1024 + s0 + r) << 10) + 512 + (kvh << 7) + hd];
  }
  __syncthreads();
  for (int j = t; j < 8192; j += 256) {
    int hd = j >> 6, col = j & 63;
    vt[((long)(bkv << 7) + hd) * 1024 + s0 + col] = tile[hd][col];
  }
}

// ---------------- Flash attention (causal, GQA), double-buffered prefetch -------
// grid = (bh=64, qtd=16), qt = 15 - qtd  (longest blocks dispatch first).
// Per tile: one barrier; next K/V tile staged via global_load_lds during compute.
__global__ __launch_bounds__(256) void attn_k(const bf16* __restrict__ qb,
                                              const bf16* __restrict__ kb,
                                              const bf16* __restrict__ vt,
                                              bf16* __restrict__ aob) {
  const int bh = blockIdx.x;            // b*16 + h
  const int qt = 15 - blockIdx.y;       // q tile, heavy-first
  const int b = bh >> 4, h = bh & 15, kv = h >> 2;
  const int t = threadIdx.x, w = t >> 6, l = t & 63, lr = l & 15, lh = l >> 4;
  __shared__ __align__(16) char Ks[2][16384];
  __shared__ __align__(16) char Vs[2][16384];
  __shared__ __align__(16) bf16 Ps[4][16][72];   // per-wave P, padded

  bf16x8 qfrag[4];
  {
    const int qrow = (qt << 6) + (w << 4) + lr;
    const bf16* qp = qb + ((long)(b * 1024 + qrow) << 11) + (h << 7);
#pragma unroll
    for (int kc = 0; kc < 4; kc++) qfrag[kc] = *(const bf16x8*)(qp + (kc << 5) + (lh << 3));
  }

  f32x4 acc[8];
#pragma unroll
  for (int i = 0; i < 8; i++) acc[i] = {0.f, 0.f, 0.f, 0.f};
  float m[4]  = {-1e30f, -1e30f, -1e30f, -1e30f};
  float ls[4] = {0.f, 0.f, 0.f, 0.f};

  const bf16* kg = kb + ((long)b << 19) + (kv << 7);     // row stride 512
  const bf16* vg = vt + ((long)(b * 4 + kv) << 17);      // row stride 1024
  const int nt = qt + 1;

  auto stage = [&](int buf, int tt2) {
    const int kv0 = tt2 << 6;
#pragma unroll
    for (int pass = 0; pass < 4; pass++) {
      int c = t + (pass << 8);
      { int row = c >> 4, slot = c & 15, gs = slot ^ (row & 7);
        gload16((void*)(kg + (long)(kv0 + row) * 512 + (gs << 3)), &Ks[buf][c * 16]); }
      { int row = c >> 3, slot = c & 7,  gs = slot ^ (row & 7);
        gload16((void*)(vg + (long)row * 1024 + kv0 + (gs << 3)), &Vs[buf][c * 16]); }
    }
  };

  stage(0, 0);
  int cur = 0;

  for (int tt = 0; tt < nt; tt++) {
    __syncthreads();                    // drains vmcnt(0): buf[cur] ready, buf[cur^1] free
    if (tt + 1 < nt) stage(cur ^ 1, tt + 1);

    // S = Q @ K^T (scale pre-folded into Q)
    f32x4 s4[4];
#pragma unroll
    for (int nf = 0; nf < 4; nf++) s4[nf] = {0.f, 0.f, 0.f, 0.f};
    __builtin_amdgcn_s_setprio(1);
#pragma unroll
    for (int nf = 0; nf < 4; nf++) {
      int key = (nf << 4) + lr;
#pragma unroll
      for (int kc = 0; kc < 4; kc++) {
        bf16x8 kf8 = *(const bf16x8*)(&Ks[cur][0] + key * 256 + (((kc << 6) + (lh << 4)) ^ ((key & 7) << 4)));
        s4[nf] = __builtin_amdgcn_mfma_f32_16x16x32_bf16(qfrag[kc], kf8, s4[nf], 0, 0, 0);
      }
    }
    __builtin_amdgcn_s_setprio(0);

    if (tt == qt) {  // causal mask on the diagonal tile
      const int kv0 = tt << 6;
#pragma unroll
      for (int nf = 0; nf < 4; nf++) {
        int key = kv0 + (nf << 4) + lr;
#pragma unroll
        for (int r = 0; r < 4; r++) {
          int qg = (qt << 6) + (w << 4) + (lh << 2) + r;
          if (key > qg) s4[nf][r] = -1e30f;
        }
      }
    }

    // online softmax with deferred rescale (T13, THR=8)
    float mc[4];
#pragma unroll
    for (int r = 0; r < 4; r++)
      mc[r] = fmaxf(fmaxf(s4[0][r], s4[1][r]), fmaxf(s4[2][r], s4[3][r]));
#pragma unroll
    for (int d = 1; d < 16; d <<= 1)
#pragma unroll
      for (int r = 0; r < 4; r++) mc[r] = fmaxf(mc[r], __shfl_xor(mc[r], d));

    int grow = 0;
#pragma unroll
    for (int r = 0; r < 4; r++) grow |= (mc[r] > m[r] + 8.f) ? 1 : 0;
    if (__any(grow)) {
      f32x4 av;
#pragma unroll
      for (int r = 0; r < 4; r++) {
        float mn = fmaxf(m[r], mc[r]);
        float al = __expf(m[r] - mn);
        m[r] = mn; ls[r] *= al; av[r] = al;
      }
#pragma unroll
      for (int hf = 0; hf < 8; hf++) acc[hf] *= av;
    }

    float rs[4] = {0.f, 0.f, 0.f, 0.f};
#pragma unroll
    for (int nf = 0; nf < 4; nf++)
#pragma unroll
      for (int r = 0; r < 4; r++) {
        float p = __expf(s4[nf][r] - m[r]);
        s4[nf][r] = p;
        rs[r] += p;
      }
#pragma unroll
    for (int d = 1; d < 16; d <<= 1)
#pragma unroll
      for (int r = 0; r < 4; r++) rs[r] += __shfl_xor(rs[r], d);
#pragma unroll
    for (int r = 0; r < 4; r++) ls[r] += rs[r];

    // P -> LDS (per-wave region; layout transpose for PV A-operand)
#pragma unroll
    for (int nf = 0; nf < 4; nf++)
#pragma unroll
      for (int r = 0; r < 4; r++)
        Ps[w][(lh << 2) + r][(nf << 4) + lr] = (bf16)s4[nf][r];

    // O += P @ V
    __builtin_amdgcn_s_setprio(1);
#pragma unroll
    for (int kc = 0; kc < 2; kc++) {
      bf16x8 pf8 = *(const bf16x8*)((const char*)&Ps[w][lr][0] + (kc << 6) + (lh << 4));
#pragma unroll
      for (int hf = 0; hf < 8; hf++) {
        int hd = (hf << 4) + lr;
        bf16x8 vf8 = *(const bf16x8*)(&Vs[cur][0] + hd * 128 + (((kc << 6) + (lh << 4)) ^ ((hd & 7) << 4)));
        acc[hf] = __builtin_amdgcn_mfma_f32_16x16x32_bf16(pf8, vf8, acc[hf], 0, 0, 0);
      }
    }
    __builtin_amdgcn_s_setprio(0);
    cur ^= 1;
  }

  float inv[4];
#pragma unroll
  for (int r = 0; r < 4; r++) inv[r] = 1.f / ls[r];
#pragma unroll
  for (int hf = 0; hf < 8; hf++)
#pragma unroll
    for (int r = 0; r < 4; r++) {
      int qrow = (qt << 6) + (w << 4) + (lh << 2) + r;
      aob[((long)(b * 1024 + qrow) << 11) + (h << 7) + (hf << 4) + lr] = (bf16)(acc[hf][r] * inv[r]);
    }
}

// ---------------- launch -----------------------------------------
extern "C" void kernel_launch(void* const* d_in, const int* in_sizes, int n_in,
                              void* d_out, int out_size, void* d_ws, size_t ws_size,
                              hipStream_t stream) {
  (void)in_sizes; (void)n_in; (void)out_size; (void)ws_size;
  const float* x  = (const float*)d_in[0];
  const float* fc = (const float*)d_in[1];
  const float* fs = (const float*)d_in[2];
  // d_in[3] = attention_mask: pure causal, implemented directly.
  const float* wq = (const float*)d_in[4];
  const float* wk = (const float*)d_in[5];
  const float* wv = (const float*)d_in[6];
  const float* wo = (const float*)d_in[7];

  float* out    = (float*)d_out;
  float* kcache = out + 8388608;   // (4,1024,4,128)
  float* vcache = out + 10485760;  // (4,1024,4,128)

  char* ws = (char*)d_ws;
  bf16*  xb   = (bf16*)(ws);                    // 16 MB
  bf16*  wqb  = (bf16*)(ws + 16777216);         // 8 MB
  bf16*  wkvb = (bf16*)(ws + 25165824);         // 4 MB (wk rows then wv rows)
  bf16*  wob  = (bf16*)(ws + 29360128);         // 8 MB
  float* kvf  = (float*)(ws + 37748736);        // 16 MB kv fp32
  bf16*  qbb  = (bf16*)(ws + 54525952);         // 16 MB q bf16 (roped, scaled)
  bf16*  kbf  = (bf16*)(ws + 71303168);         // 4 MB k bf16 (roped)
  bf16*  vtb  = (bf16*)(ws + 75497472);         // 4 MB v^T bf16
  bf16*  aob  = (bf16*)(ws + 79691776);         // 16 MB attn out bf16
  // total ws use: ~92 MB

  cast_all<<<18432, 256, 0, stream>>>((const float4*)x, (const float4*)wq,
                                      (const float4*)wk, (const float4*)wv,
                                      (const float4*)wo,
                                      (bf16x4*)xb, (bf16x4*)wqb, (bf16x4*)wkvb, (bf16x4*)wob);

  gemm_q <<<dim3(16, 32), 256, 0, stream>>>(xb, wqb, qbb, fc, fs, 4096, 2048, 2048);
  gemm_bt<<<dim3(8, 32),  256, 0, stream>>>(xb, wkvb, kvf, 4096, 1024, 2048);

  rope_pack_kv<<<4096, 256, 0, stream>>>(kvf, fc, fs, kbf, kcache, vcache);
  vtrans<<<dim3(16, 16), 256, 0, stream>>>(kvf, vtb);

  attn_k<<<dim3(64, 16), 256, 0, stream>>>(qbb, kbf, vtb, aob);

  gemm_bt<<<dim3(16, 32), 256, 0, stream>>>(aob, wob, out, 4096, 2048, 2048);
}

// Round 3
// 199.439 us; speedup vs baseline: 1.4821x; 1.1790x over previous
//
#include <hip/hip_runtime.h>

typedef __bf16 bf16;
typedef __bf16 bf16x8 __attribute__((ext_vector_type(8)));
typedef __bf16 bf16x4 __attribute__((ext_vector_type(4)));
typedef float  f32x4  __attribute__((ext_vector_type(4)));

#define AS1 __attribute__((address_space(1)))
#define AS3 __attribute__((address_space(3)))

__device__ __forceinline__ void gload16(void* g, void* l) {
  __builtin_amdgcn_global_load_lds((AS1 void*)g, (AS3 void*)l, 16, 0, 0);
}

// ---------------- fused cast fp32 -> bf16 for x + all weights ----------------
__global__ void cast_all(const float4* __restrict__ x,  const float4* __restrict__ wq,
                         const float4* __restrict__ wk, const float4* __restrict__ wv,
                         const float4* __restrict__ wo,
                         bf16x4* __restrict__ xb, bf16x4* __restrict__ wqb,
                         bf16x4* __restrict__ wkvb, bf16x4* __restrict__ wob) {
  long i = (long)blockIdx.x * 256 + threadIdx.x;
  float4 v; bf16x4* dp;
  if (i < 2097152)      { v = x[i];            dp = xb + i; }
  else if (i < 3145728) { v = wq[i - 2097152]; dp = wqb + (i - 2097152); }
  else if (i < 3407872) { v = wk[i - 3145728]; dp = wkvb + (i - 3145728); }
  else if (i < 3670016) { v = wv[i - 3407872]; dp = wkvb + 262144 + (i - 3407872); }
  else                  { v = wo[i - 3670016]; dp = wob + (i - 3670016); }
  bf16x4 o;
  o[0] = (bf16)v.x; o[1] = (bf16)v.y; o[2] = (bf16)v.z; o[3] = (bf16)v.w;
  *dp = o;
}

// =====================================================================
// 256x256 8-phase GEMM (T2-equivalent swizzle + T3/T4 counted vmcnt + T5).
// C[M,N] = A[M,2048] * Bt[N,2048]^T. 8 waves (2Mx4N), per-wave 128x64.
// BK=64, 2 K-tiles per iteration, 1 half-tile (16KB) staged per phase.
// epi=0: fp32 C.  epi=1: QKV fused epilogue (rope-Q/rope-K/V-transpose).
// =====================================================================
#define PH_OPEN12 \
  asm volatile("s_waitcnt lgkmcnt(8)" ::: "memory"); \
  __builtin_amdgcn_s_barrier(); \
  asm volatile("s_waitcnt lgkmcnt(0)" ::: "memory"); \
  __builtin_amdgcn_sched_barrier(0); \
  __builtin_amdgcn_s_setprio(1);

#define PH_OPEN \
  __builtin_amdgcn_s_barrier(); \
  asm volatile("s_waitcnt lgkmcnt(0)" ::: "memory"); \
  __builtin_amdgcn_sched_barrier(0); \
  __builtin_amdgcn_s_setprio(1);

#define PH_CLOSE \
  __builtin_amdgcn_s_setprio(0); \
  __builtin_amdgcn_sched_barrier(0); \
  __builtin_amdgcn_s_barrier();

#define MFMAQ(q) \
  _Pragma("unroll") for (int kk = 0; kk < 2; kk++) \
  _Pragma("unroll") for (int m2 = 0; m2 < 2; m2++) \
  _Pragma("unroll") for (int ni = 0; ni < 4; ni++) \
    acc[(q)*2+m2][ni] = __builtin_amdgcn_mfma_f32_16x16x32_bf16(af[m2][kk], bfr[ni][kk], acc[(q)*2+m2][ni], 0, 0, 0);

__global__ __launch_bounds__(512, 2) void gemm8(const bf16* __restrict__ A,
                                                const bf16* __restrict__ Bt,
                                                int N, int epi,
                                                float* __restrict__ Cf,
                                                bf16* __restrict__ qbb,
                                                bf16* __restrict__ kbf,
                                                float* __restrict__ kcache,
                                                float* __restrict__ vcache,
                                                bf16* __restrict__ vtb,
                                                const float* __restrict__ fc,
                                                const float* __restrict__ fs) {
  __shared__ __align__(16) char As[2][32768];
  __shared__ __align__(16) char Bs[2][32768];
  const int t = threadIdx.x;
  const int w = t >> 6, l = t & 63, lr = l & 15, lh = l >> 4;
  const int wr = w >> 2, wc = w & 3;
  const int m0 = blockIdx.y << 8, n0 = blockIdx.x << 8;

  f32x4 acc[8][4];
#pragma unroll
  for (int i = 0; i < 8; i++)
#pragma unroll
    for (int j = 0; j < 4; j++) acc[i][j] = {0.f, 0.f, 0.f, 0.f};

  // staging: half-tile = 128 rows x 64 cols bf16 = 16KB = 512thr x 2 x 16B
  auto stA = [&](int buf, int half, int kt) {
#pragma unroll
    for (int p = 0; p < 2; p++) {
      int c = t + (p << 9);
      int rl = c >> 3, sl = c & 7, gs = sl ^ ((rl >> 1) & 3);
      gload16((void*)(A + (long)(m0 + (half << 7) + rl) * 2048 + (kt << 6) + (gs << 3)),
              &As[buf][(half << 14) + (c << 4)]);
    }
  };
  auto stB = [&](int buf, int half, int kt) {
#pragma unroll
    for (int p = 0; p < 2; p++) {
      int c = t + (p << 9);
      int rl = c >> 3, sl = c & 7, gs = sl ^ ((rl >> 1) & 3);
      gload16((void*)(Bt + (long)(n0 + (half << 7) + rl) * 2048 + (kt << 6) + (gs << 3)),
              &Bs[buf][(half << 14) + (c << 4)]);
    }
  };
  // fragment reads (row-keyed slot XOR; measured conflict-free pattern)
  auto rdA = [&](int buf, int mi, int kk) -> bf16x8 {
    int row = (wr << 7) + (mi << 4) + lr;
    int sl  = ((kk << 2) | lh) ^ ((row >> 1) & 3);
    return *(const bf16x8*)(&As[buf][row * 128 + (sl << 4)]);
  };
  auto rdB = [&](int buf, int ni, int kk) -> bf16x8 {
    int row = (wc << 6) + (ni << 4) + lr;
    int sl  = ((kk << 2) | lh) ^ ((row >> 1) & 3);
    return *(const bf16x8*)(&Bs[buf][row * 128 + (sl << 4)]);
  };

  // ---- prologue: tile0 (A+B) -> buf0, tile1 (B only) -> buf1 ----
  stB(0, 0, 0); stB(0, 1, 0);
  stA(0, 0, 0); stA(0, 1, 0);
  stB(1, 0, 1); stB(1, 1, 1);
  asm volatile("s_waitcnt vmcnt(4)" ::: "memory");   // tile0 landed; tile1.B in flight
  __builtin_amdgcn_s_barrier();

  const int NI = 16;   // K=2048 / 128
  for (int j = 0; j < NI; j++) {
    const int ktE = 2 * j, ktO = 2 * j + 1;
    const bool last = (j == NI - 1);
    bf16x8 bfr[4][2], af[2][2];

    // ---- phase 1: tile E (buf0), quadrant 0; stage O.A0 ----
#pragma unroll
    for (int ni = 0; ni < 4; ni++) { bfr[ni][0] = rdB(0, ni, 0); bfr[ni][1] = rdB(0, ni, 1); }
    af[0][0] = rdA(0, 0, 0); af[0][1] = rdA(0, 0, 1);
    af[1][0] = rdA(0, 1, 0); af[1][1] = rdA(0, 1, 1);
    stA(1, 0, ktO);
    PH_OPEN12; MFMAQ(0); PH_CLOSE;

    // ---- phase 2: quadrant 1; stage O.A1 ----
    af[0][0] = rdA(0, 2, 0); af[0][1] = rdA(0, 2, 1);
    af[1][0] = rdA(0, 3, 0); af[1][1] = rdA(0, 3, 1);
    stA(1, 1, ktO);
    PH_OPEN; MFMAQ(1); PH_CLOSE;

    // ---- phase 3: quadrant 2; stage E'.B0 (buf0.B free since ph1) ----
    af[0][0] = rdA(0, 4, 0); af[0][1] = rdA(0, 4, 1);
    af[1][0] = rdA(0, 5, 0); af[1][1] = rdA(0, 5, 1);
    if (!last) stB(0, 0, ktE + 2);
    PH_OPEN; MFMAQ(2); PH_CLOSE;

    // ---- phase 4: quadrant 3; stage E'.B1; counted wait for tile O ----
    af[0][0] = rdA(0, 6, 0); af[0][1] = rdA(0, 6, 1);
    af[1][0] = rdA(0, 7, 0); af[1][1] = rdA(0, 7, 1);
    if (!last) stB(0, 1, ktE + 2);
    PH_OPEN;  MFMAQ(3);
    __builtin_amdgcn_s_setprio(0);
    __builtin_amdgcn_sched_barrier(0);
    if (last) { asm volatile("s_waitcnt vmcnt(0)" ::: "memory"); }
    else      { asm volatile("s_waitcnt vmcnt(4)" ::: "memory"); }
    __builtin_amdgcn_s_barrier();

    // ---- phase 5: tile O (buf1), quadrant 0; stage E'.A0 ----
#pragma unroll
    for (int ni = 0; ni < 4; ni++) { bfr[ni][0] = rdB(1, ni, 0); bfr[ni][1] = rdB(1, ni, 1); }
    af[0][0] = rdA(1, 0, 0); af[0][1] = rdA(1, 0, 1);
    af[1][0] = rdA(1, 1, 0); af[1][1] = rdA(1, 1, 1);
    if (!last) stA(0, 0, ktE + 2);
    PH_OPEN12; MFMAQ(0); PH_CLOSE;

    // ---- phase 6: quadrant 1; stage E'.A1 ----
    af[0][0] = rdA(1, 2, 0); af[0][1] = rdA(1, 2, 1);
    af[1][0] = rdA(1, 3, 0); af[1][1] = rdA(1, 3, 1);
    if (!last) stA(0, 1, ktE + 2);
    PH_OPEN; MFMAQ(1); PH_CLOSE;

    // ---- phase 7: quadrant 2; stage O'.B0 (buf1.B free since ph5) ----
    af[0][0] = rdA(1, 4, 0); af[0][1] = rdA(1, 4, 1);
    af[1][0] = rdA(1, 5, 0); af[1][1] = rdA(1, 5, 1);
    if (!last) stB(1, 0, ktO + 2);
    PH_OPEN; MFMAQ(2); PH_CLOSE;

    // ---- phase 8: quadrant 3; stage O'.B1; counted wait for tile E' ----
    af[0][0] = rdA(1, 6, 0); af[0][1] = rdA(1, 6, 1);
    af[1][0] = rdA(1, 7, 0); af[1][1] = rdA(1, 7, 1);
    if (!last) stB(1, 1, ktO + 2);
    PH_OPEN; MFMAQ(3);
    __builtin_amdgcn_s_setprio(0);
    __builtin_amdgcn_sched_barrier(0);
    if (!last) { asm volatile("s_waitcnt vmcnt(4)" ::: "memory"); }
    __builtin_amdgcn_s_barrier();
  }

  // ------------------------- epilogue -------------------------
  if (epi == 0) {
#pragma unroll
    for (int mi = 0; mi < 8; mi++)
#pragma unroll
      for (int ni = 0; ni < 4; ni++) {
        int col  = n0 + (wc << 6) + (ni << 4) + lr;
        int rowb = m0 + (wr << 7) + (mi << 4) + (lh << 2);
#pragma unroll
        for (int r = 0; r < 4; r++)
          Cf[(long)(rowb + r) * N + col] = acc[mi][ni][r];
      }
  } else if (n0 < 2048) {          // ---- Q: rope + 1/sqrt(HD), bf16 ----
    const float qs = 0.08838834764831845f;
    const int im = lr & 1;
#pragma unroll
    for (int mi = 0; mi < 8; mi++)
#pragma unroll
      for (int ni = 0; ni < 4; ni++) {
        int col  = n0 + (wc << 6) + (ni << 4) + lr;
        int i2   = (col & 127) >> 1;
        int rowb = m0 + (wr << 7) + (mi << 4) + (lh << 2);
#pragma unroll
        for (int r = 0; r < 4; r++) {
          int row = rowb + r, s = row & 1023;
          float c = fc[(s << 6) + i2], sn = fs[(s << 6) + i2];
          float own = acc[mi][ni][r], oth = __shfl_xor(own, 1);
          float xr = im ? oth : own, xi = im ? own : oth;
          float val = im ? (xr * sn + xi * c) : (xr * c - xi * sn);
          qbb[(long)row * 2048 + col] = (bf16)(val * qs);
        }
      }
  } else if (n0 < 2560) {          // ---- K: rope, bf16 + fp32 cache ----
    const int im = lr & 1;
#pragma unroll
    for (int mi = 0; mi < 8; mi++)
#pragma unroll
      for (int ni = 0; ni < 4; ni++) {
        int col  = n0 + (wc << 6) + (ni << 4) + lr;
        int ck   = col - 2048;
        int i2   = (ck & 127) >> 1;
        int rowb = m0 + (wr << 7) + (mi << 4) + (lh << 2);
#pragma unroll
        for (int r = 0; r < 4; r++) {
          int row = rowb + r, s = row & 1023;
          float c = fc[(s << 6) + i2], sn = fs[(s << 6) + i2];
          float own = acc[mi][ni][r], oth = __shfl_xor(own, 1);
          float xr = im ? oth : own, xi = im ? own : oth;
          float val = im ? (xr * sn + xi * c) : (xr * c - xi * sn);
          kbf[(long)row * 512 + ck] = (bf16)val;
          kcache[(long)row * 512 + ck] = val;
        }
      }
  } else {                          // ---- V: fp32 cache + transposed bf16 ----
#pragma unroll
    for (int mi = 0; mi < 8; mi++)
#pragma unroll
      for (int ni = 0; ni < 4; ni++) {
        int col  = n0 + (wc << 6) + (ni << 4) + lr;
        int cv   = col - 2560;
        int rowb = m0 + (wr << 7) + (mi << 4) + (lh << 2);
        bf16x4 pk;
#pragma unroll
        for (int r = 0; r < 4; r++) {
          float v = acc[mi][ni][r];
          vcache[(long)(rowb + r) * 512 + cv] = v;
          pk[r] = (bf16)v;
        }
        int b = rowb >> 10, s0 = rowb & 1023;
        *(bf16x4*)(vtb + ((long)((b << 2) + (cv >> 7)) * 128 + (cv & 127)) * 1024 + s0) = pk;
      }
  }
}

// ---------------- Flash attention (causal, GQA), double-buffered prefetch -------
__global__ __launch_bounds__(256) void attn_k(const bf16* __restrict__ qb,
                                              const bf16* __restrict__ kb,
                                              const bf16* __restrict__ vt,
                                              bf16* __restrict__ aob) {
  const int bh = blockIdx.x;
  const int qt = 15 - blockIdx.y;       // heavy-first
  const int b = bh >> 4, h = bh & 15, kv = h >> 2;
  const int t = threadIdx.x, w = t >> 6, l = t & 63, lr = l & 15, lh = l >> 4;
  __shared__ __align__(16) char Ks[2][16384];
  __shared__ __align__(16) char Vs[2][16384];
  __shared__ __align__(16) bf16 Ps[4][16][72];

  bf16x8 qfrag[4];
  {
    const int qrow = (qt << 6) + (w << 4) + lr;
    const bf16* qp = qb + ((long)(b * 1024 + qrow) << 11) + (h << 7);
#pragma unroll
    for (int kc = 0; kc < 4; kc++) qfrag[kc] = *(const bf16x8*)(qp + (kc << 5) + (lh << 3));
  }

  f32x4 acc[8];
#pragma unroll
  for (int i = 0; i < 8; i++) acc[i] = {0.f, 0.f, 0.f, 0.f};
  float m[4]  = {-1e30f, -1e30f, -1e30f, -1e30f};
  float ls[4] = {0.f, 0.f, 0.f, 0.f};

  const bf16* kg = kb + ((long)b << 19) + (kv << 7);
  const bf16* vg = vt + ((long)(b * 4 + kv) << 17);
  const int nt = qt + 1;

  auto stage = [&](int buf, int tt2) {
    const int kv0 = tt2 << 6;
#pragma unroll
    for (int pass = 0; pass < 4; pass++) {
      int c = t + (pass << 8);
      { int row = c >> 4, slot = c & 15, gs = slot ^ (row & 7);
        gload16((void*)(kg + (long)(kv0 + row) * 512 + (gs << 3)), &Ks[buf][c * 16]); }
      { int row = c >> 3, slot = c & 7,  gs = slot ^ (row & 7);
        gload16((void*)(vg + (long)row * 1024 + kv0 + (gs << 3)), &Vs[buf][c * 16]); }
    }
  };

  stage(0, 0);
  int cur = 0;

  for (int tt = 0; tt < nt; tt++) {
    __syncthreads();
    if (tt + 1 < nt) stage(cur ^ 1, tt + 1);

    f32x4 s4[4];
#pragma unroll
    for (int nf = 0; nf < 4; nf++) s4[nf] = {0.f, 0.f, 0.f, 0.f};
    __builtin_amdgcn_s_setprio(1);
#pragma unroll
    for (int nf = 0; nf < 4; nf++) {
      int key = (nf << 4) + lr;
#pragma unroll
      for (int kc = 0; kc < 4; kc++) {
        bf16x8 kf8 = *(const bf16x8*)(&Ks[cur][0] + key * 256 + (((kc << 6) + (lh << 4)) ^ ((key & 7) << 4)));
        s4[nf] = __builtin_amdgcn_mfma_f32_16x16x32_bf16(qfrag[kc], kf8, s4[nf], 0, 0, 0);
      }
    }
    __builtin_amdgcn_s_setprio(0);

    if (tt == qt) {
      const int kv0 = tt << 6;
#pragma unroll
      for (int nf = 0; nf < 4; nf++) {
        int key = kv0 + (nf << 4) + lr;
#pragma unroll
        for (int r = 0; r < 4; r++) {
          int qg = (qt << 6) + (w << 4) + (lh << 2) + r;
          if (key > qg) s4[nf][r] = -1e30f;
        }
      }
    }

    float mc[4];
#pragma unroll
    for (int r = 0; r < 4; r++)
      mc[r] = fmaxf(fmaxf(s4[0][r], s4[1][r]), fmaxf(s4[2][r], s4[3][r]));
#pragma unroll
    for (int d = 1; d < 16; d <<= 1)
#pragma unroll
      for (int r = 0; r < 4; r++) mc[r] = fmaxf(mc[r], __shfl_xor(mc[r], d));

    int grow = 0;
#pragma unroll
    for (int r = 0; r < 4; r++) grow |= (mc[r] > m[r] + 8.f) ? 1 : 0;
    if (__any(grow)) {
      f32x4 av;
#pragma unroll
      for (int r = 0; r < 4; r++) {
        float mn = fmaxf(m[r], mc[r]);
        float al = __expf(m[r] - mn);
        m[r] = mn; ls[r] *= al; av[r] = al;
      }
#pragma unroll
      for (int hf = 0; hf < 8; hf++) acc[hf] *= av;
    }

    float rs[4] = {0.f, 0.f, 0.f, 0.f};
#pragma unroll
    for (int nf = 0; nf < 4; nf++)
#pragma unroll
      for (int r = 0; r < 4; r++) {
        float p = __expf(s4[nf][r] - m[r]);
        s4[nf][r] = p;
        rs[r] += p;
      }
#pragma unroll
    for (int d = 1; d < 16; d <<= 1)
#pragma unroll
      for (int r = 0; r < 4; r++) rs[r] += __shfl_xor(rs[r], d);
#pragma unroll
    for (int r = 0; r < 4; r++) ls[r] += rs[r];

#pragma unroll
    for (int nf = 0; nf < 4; nf++)
#pragma unroll
      for (int r = 0; r < 4; r++)
        Ps[w][(lh << 2) + r][(nf << 4) + lr] = (bf16)s4[nf][r];

    __builtin_amdgcn_s_setprio(1);
#pragma unroll
    for (int kc = 0; kc < 2; kc++) {
      bf16x8 pf8 = *(const bf16x8*)((const char*)&Ps[w][lr][0] + (kc << 6) + (lh << 4));
#pragma unroll
      for (int hf = 0; hf < 8; hf++) {
        int hd = (hf << 4) + lr;
        bf16x8 vf8 = *(const bf16x8*)(&Vs[cur][0] + hd * 128 + (((kc << 6) + (lh << 4)) ^ ((hd & 7) << 4)));
        acc[hf] = __builtin_amdgcn_mfma_f32_16x16x32_bf16(pf8, vf8, acc[hf], 0, 0, 0);
      }
    }
    __builtin_amdgcn_s_setprio(0);
    cur ^= 1;
  }

  float inv[4];
#pragma unroll
  for (int r = 0; r < 4; r++) inv[r] = 1.f / ls[r];
#pragma unroll
  for (int hf = 0; hf < 8; hf++)
#pragma unroll
    for (int r = 0; r < 4; r++) {
      int qrow = (qt << 6) + (w << 4) + (lh << 2) + r;
      aob[((long)(b * 1024 + qrow) << 11) + (h << 7) + (hf << 4) + lr] = (bf16)(acc[hf][r] * inv[r]);
    }
}

// ---------------- launch -----------------------------------------
extern "C" void kernel_launch(void* const* d_in, const int* in_sizes, int n_in,
                              void* d_out, int out_size, void* d_ws, size_t ws_size,
                              hipStream_t stream) {
  (void)in_sizes; (void)n_in; (void)out_size; (void)ws_size;
  const float* x  = (const float*)d_in[0];
  const float* fc = (const float*)d_in[1];
  const float* fs = (const float*)d_in[2];
  // d_in[3] = attention_mask: pure causal, implemented directly.
  const float* wq = (const float*)d_in[4];
  const float* wk = (const float*)d_in[5];
  const float* wv = (const float*)d_in[6];
  const float* wo = (const float*)d_in[7];

  float* out    = (float*)d_out;
  float* kcache = out + 8388608;   // (4,1024,4,128)
  float* vcache = out + 10485760;  // (4,1024,4,128)

  char* ws = (char*)d_ws;
  bf16* xb    = (bf16*)(ws);                    // 16 MB
  bf16* wqkv  = (bf16*)(ws + 16777216);         // 12 MB: [wq 8 | wk 2 | wv 2]
  bf16* wob   = (bf16*)(ws + 29360128);         // 8 MB
  bf16* qbb   = (bf16*)(ws + 54525952);         // 16 MB q bf16 (roped, scaled)
  bf16* kbf   = (bf16*)(ws + 71303168);         // 4 MB k bf16 (roped)
  bf16* vtb   = (bf16*)(ws + 75497472);         // 4 MB v^T bf16
  bf16* aob   = (bf16*)(ws + 79691776);         // 16 MB attn out bf16

  cast_all<<<18432, 256, 0, stream>>>((const float4*)x, (const float4*)wq,
                                      (const float4*)wk, (const float4*)wv,
                                      (const float4*)wo,
                                      (bf16x4*)xb, (bf16x4*)wqkv,
                                      (bf16x4*)(wqkv + 4194304), (bf16x4*)wob);

  // fused QKV projection + rope + caches + V-transpose
  gemm8<<<dim3(12, 16), 512, 0, stream>>>(xb, wqkv, 3072, 1, nullptr,
                                          qbb, kbf, kcache, vcache, vtb, fc, fs);

  attn_k<<<dim3(64, 16), 256, 0, stream>>>(qbb, kbf, vtb, aob);

  // output projection
  gemm8<<<dim3(8, 16), 512, 0, stream>>>(aob, wob, 2048, 0, out,
                                         nullptr, nullptr, nullptr, nullptr, nullptr,
                                         nullptr, nullptr);
}

// Round 4
// 174.796 us; speedup vs baseline: 1.6911x; 1.1410x over previous
//
#include <hip/hip_runtime.h>

typedef __bf16 bf16;
typedef __bf16 bf16x8 __attribute__((ext_vector_type(8)));
typedef __bf16 bf16x4 __attribute__((ext_vector_type(4)));
typedef float  f32x4  __attribute__((ext_vector_type(4)));

#define AS1 __attribute__((address_space(1)))
#define AS3 __attribute__((address_space(3)))

__device__ __forceinline__ void gload16(void* g, void* l) {
  __builtin_amdgcn_global_load_lds((AS1 void*)g, (AS3 void*)l, 16, 0, 0);
}

// ---------------- fused cast fp32 -> bf16 for x + all weights ----------------
__global__ void cast_all(const float4* __restrict__ x,  const float4* __restrict__ wq,
                         const float4* __restrict__ wk, const float4* __restrict__ wv,
                         const float4* __restrict__ wo,
                         bf16x4* __restrict__ xb, bf16x4* __restrict__ wqb,
                         bf16x4* __restrict__ wkvb, bf16x4* __restrict__ wob) {
  long i = (long)blockIdx.x * 256 + threadIdx.x;
  float4 v; bf16x4* dp;
  if (i < 2097152)      { v = x[i];            dp = xb + i; }
  else if (i < 3145728) { v = wq[i - 2097152]; dp = wqb + (i - 2097152); }
  else if (i < 3407872) { v = wk[i - 3145728]; dp = wkvb + (i - 3145728); }
  else if (i < 3670016) { v = wv[i - 3407872]; dp = wkvb + 262144 + (i - 3407872); }
  else                  { v = wo[i - 3670016]; dp = wob + (i - 3670016); }
  bf16x4 o;
  o[0] = (bf16)v.x; o[1] = (bf16)v.y; o[2] = (bf16)v.z; o[3] = (bf16)v.w;
  *dp = o;
}

// =====================================================================
// 8-phase GEMM, BM=256, BN=64*NFR (NFR=4 -> 256x256, NFR=2 -> 256x128).
// C[M,N] = A[M,2048] * Bt[N,2048]^T. 8 waves (2M x 4N), per-wave 128 x 16*NFR.
// BK=64, 2 K-tiles/iter, counted vmcnt (never 0 in steady state).
// LDS swizzle: slot ^= (row & 7)  [full 8-slot spread -> conflict-free b128].
// epi=0: fp32 C.  epi=1: QKV fused epilogue (rope-Q / rope-K / V-transpose).
// =====================================================================
#define PH_OPEN12 \
  asm volatile("s_waitcnt lgkmcnt(8)" ::: "memory"); \
  __builtin_amdgcn_s_barrier(); \
  asm volatile("s_waitcnt lgkmcnt(0)" ::: "memory"); \
  __builtin_amdgcn_sched_barrier(0); \
  __builtin_amdgcn_s_setprio(1);

#define PH_OPEN \
  __builtin_amdgcn_s_barrier(); \
  asm volatile("s_waitcnt lgkmcnt(0)" ::: "memory"); \
  __builtin_amdgcn_sched_barrier(0); \
  __builtin_amdgcn_s_setprio(1);

#define PH_CLOSE \
  __builtin_amdgcn_s_setprio(0); \
  __builtin_amdgcn_sched_barrier(0); \
  __builtin_amdgcn_s_barrier();

#define MFMAQ(q) \
  _Pragma("unroll") for (int kk = 0; kk < 2; kk++) \
  _Pragma("unroll") for (int m2 = 0; m2 < 2; m2++) \
  _Pragma("unroll") for (int ni = 0; ni < NFR; ni++) \
    acc[(q)*2+m2][ni] = __builtin_amdgcn_mfma_f32_16x16x32_bf16(af[m2][kk], bfr[ni][kk], acc[(q)*2+m2][ni], 0, 0, 0);

template<int NFR>
__global__ __launch_bounds__(512, 2) void gemm8(const bf16* __restrict__ A,
                                                const bf16* __restrict__ Bt,
                                                int N, int epi,
                                                float* __restrict__ Cf,
                                                bf16* __restrict__ qbb,
                                                bf16* __restrict__ kbf,
                                                float* __restrict__ kcache,
                                                float* __restrict__ vcache,
                                                bf16* __restrict__ vtb,
                                                const float* __restrict__ fc,
                                                const float* __restrict__ fs) {
  __shared__ __align__(16) char As[2][32768];
  __shared__ __align__(16) char Bs[2][8192 * NFR];
  const int t = threadIdx.x;
  const int w = t >> 6, l = t & 63, lr = l & 15, lh = l >> 4;
  const int wr = w >> 2, wc = w & 3;
  const int m0 = blockIdx.y << 8, n0 = blockIdx.x * (NFR * 64);

  f32x4 acc[8][NFR];
#pragma unroll
  for (int i = 0; i < 8; i++)
#pragma unroll
    for (int j = 0; j < NFR; j++) acc[i][j] = {0.f, 0.f, 0.f, 0.f};

  // A half-tile = 128 rows x 64 cols bf16 = 16KB = 512thr x 2 x 16B
  auto stA = [&](int buf, int half, int kt) {
#pragma unroll
    for (int p = 0; p < 2; p++) {
      int c = t + (p << 9);
      int rl = c >> 3, sl = c & 7, gs = sl ^ (rl & 7);
      gload16((void*)(A + (long)(m0 + (half << 7) + rl) * 2048 + (kt << 6) + (gs << 3)),
              &As[buf][(half << 14) + (c << 4)]);
    }
  };
  // B half-tile = (NFR*32) rows x 64 cols = 4KB*NFR = 512thr x (NFR/2) x 16B
  auto stB = [&](int buf, int half, int kt) {
#pragma unroll
    for (int p = 0; p < NFR / 2; p++) {
      int c = t + (p << 9);
      int rl = c >> 3, sl = c & 7, gs = sl ^ (rl & 7);
      gload16((void*)(Bt + (long)(n0 + half * (NFR * 32) + rl) * 2048 + (kt << 6) + (gs << 3)),
              &Bs[buf][half * (NFR * 4096) + (c << 4)]);
    }
  };
  // fragment reads: slot = ((kk<<2)|lh) ^ (row&7)  -> 2 lanes/slot = free
  auto rdA = [&](int buf, int mi, int kk) -> bf16x8 {
    int row = (wr << 7) + (mi << 4) + lr;
    int sl  = ((kk << 2) | lh) ^ (row & 7);
    return *(const bf16x8*)(&As[buf][row * 128 + (sl << 4)]);
  };
  auto rdB = [&](int buf, int ni, int kk) -> bf16x8 {
    int row = wc * (NFR * 16) + (ni << 4) + lr;
    int sl  = ((kk << 2) | lh) ^ (row & 7);
    return *(const bf16x8*)(&Bs[buf][row * 128 + (sl << 4)]);
  };

  // ---- prologue: tile0 (A+B) -> buf0, tile1 (B only) -> buf1 ----
  stB(0, 0, 0); stB(0, 1, 0);
  stA(0, 0, 0); stA(0, 1, 0);
  stB(1, 0, 1); stB(1, 1, 1);
  if constexpr (NFR == 4) { asm volatile("s_waitcnt vmcnt(4)" ::: "memory"); }
  else                    { asm volatile("s_waitcnt vmcnt(2)" ::: "memory"); }
  __builtin_amdgcn_s_barrier();

  const int NI = 16;   // K=2048 / 128
  for (int j = 0; j < NI; j++) {
    const int ktE = 2 * j, ktO = 2 * j + 1;
    const bool last = (j == NI - 1);
    bf16x8 bfr[NFR][2], af[2][2];

    // ---- phase 1: tile E (buf0), quadrant 0; stage O.A0 ----
#pragma unroll
    for (int ni = 0; ni < NFR; ni++) { bfr[ni][0] = rdB(0, ni, 0); bfr[ni][1] = rdB(0, ni, 1); }
    af[0][0] = rdA(0, 0, 0); af[0][1] = rdA(0, 0, 1);
    af[1][0] = rdA(0, 1, 0); af[1][1] = rdA(0, 1, 1);
    stA(1, 0, ktO);
    PH_OPEN12; MFMAQ(0); PH_CLOSE;

    // ---- phase 2: quadrant 1; stage O.A1 ----
    af[0][0] = rdA(0, 2, 0); af[0][1] = rdA(0, 2, 1);
    af[1][0] = rdA(0, 3, 0); af[1][1] = rdA(0, 3, 1);
    stA(1, 1, ktO);
    PH_OPEN; MFMAQ(1); PH_CLOSE;

    // ---- phase 3: quadrant 2; stage E'.B0 (buf0.B free since ph1) ----
    af[0][0] = rdA(0, 4, 0); af[0][1] = rdA(0, 4, 1);
    af[1][0] = rdA(0, 5, 0); af[1][1] = rdA(0, 5, 1);
    if (!last) stB(0, 0, ktE + 2);
    PH_OPEN; MFMAQ(2); PH_CLOSE;

    // ---- phase 4: quadrant 3; stage E'.B1; counted wait for tile O ----
    af[0][0] = rdA(0, 6, 0); af[0][1] = rdA(0, 6, 1);
    af[1][0] = rdA(0, 7, 0); af[1][1] = rdA(0, 7, 1);
    if (!last) stB(0, 1, ktE + 2);
    PH_OPEN;  MFMAQ(3);
    __builtin_amdgcn_s_setprio(0);
    __builtin_amdgcn_sched_barrier(0);
    if (last)               { asm volatile("s_waitcnt vmcnt(0)" ::: "memory"); }
    else if constexpr (NFR == 4) { asm volatile("s_waitcnt vmcnt(4)" ::: "memory"); }
    else                    { asm volatile("s_waitcnt vmcnt(2)" ::: "memory"); }
    __builtin_amdgcn_s_barrier();

    // ---- phase 5: tile O (buf1), quadrant 0; stage E'.A0 ----
#pragma unroll
    for (int ni = 0; ni < NFR; ni++) { bfr[ni][0] = rdB(1, ni, 0); bfr[ni][1] = rdB(1, ni, 1); }
    af[0][0] = rdA(1, 0, 0); af[0][1] = rdA(1, 0, 1);
    af[1][0] = rdA(1, 1, 0); af[1][1] = rdA(1, 1, 1);
    if (!last) stA(0, 0, ktE + 2);
    PH_OPEN12; MFMAQ(0); PH_CLOSE;

    // ---- phase 6: quadrant 1; stage E'.A1 ----
    af[0][0] = rdA(1, 2, 0); af[0][1] = rdA(1, 2, 1);
    af[1][0] = rdA(1, 3, 0); af[1][1] = rdA(1, 3, 1);
    if (!last) stA(0, 1, ktE + 2);
    PH_OPEN; MFMAQ(1); PH_CLOSE;

    // ---- phase 7: quadrant 2; stage O'.B0 (buf1.B free since ph5) ----
    af[0][0] = rdA(1, 4, 0); af[0][1] = rdA(1, 4, 1);
    af[1][0] = rdA(1, 5, 0); af[1][1] = rdA(1, 5, 1);
    if (!last) stB(1, 0, ktO + 2);
    PH_OPEN; MFMAQ(2); PH_CLOSE;

    // ---- phase 8: quadrant 3; stage O'.B1; counted wait for tile E' ----
    af[0][0] = rdA(1, 6, 0); af[0][1] = rdA(1, 6, 1);
    af[1][0] = rdA(1, 7, 0); af[1][1] = rdA(1, 7, 1);
    if (!last) stB(1, 1, ktO + 2);
    PH_OPEN; MFMAQ(3);
    __builtin_amdgcn_s_setprio(0);
    __builtin_amdgcn_sched_barrier(0);
    if (!last) {
      if constexpr (NFR == 4) { asm volatile("s_waitcnt vmcnt(4)" ::: "memory"); }
      else                    { asm volatile("s_waitcnt vmcnt(2)" ::: "memory"); }
    }
    __builtin_amdgcn_s_barrier();
  }

  // ------------------------- epilogue -------------------------
  if (epi == 0) {
#pragma unroll
    for (int mi = 0; mi < 8; mi++)
#pragma unroll
      for (int ni = 0; ni < NFR; ni++) {
        int col  = n0 + wc * (NFR * 16) + (ni << 4) + lr;
        int rowb = m0 + (wr << 7) + (mi << 4) + (lh << 2);
#pragma unroll
        for (int r = 0; r < 4; r++)
          Cf[(long)(rowb + r) * N + col] = acc[mi][ni][r];
      }
  } else if (n0 < 2048) {          // ---- Q: rope + 1/sqrt(HD), bf16 ----
    const float qs = 0.08838834764831845f;
    const int im = lr & 1;
#pragma unroll
    for (int mi = 0; mi < 8; mi++)
#pragma unroll
      for (int ni = 0; ni < NFR; ni++) {
        int col  = n0 + wc * (NFR * 16) + (ni << 4) + lr;
        int i2   = (col & 127) >> 1;
        int rowb = m0 + (wr << 7) + (mi << 4) + (lh << 2);
#pragma unroll
        for (int r = 0; r < 4; r++) {
          int row = rowb + r, s = row & 1023;
          float c = fc[(s << 6) + i2], sn = fs[(s << 6) + i2];
          float own = acc[mi][ni][r], oth = __shfl_xor(own, 1);
          float xr = im ? oth : own, xi = im ? own : oth;
          float val = im ? (xr * sn + xi * c) : (xr * c - xi * sn);
          qbb[(long)row * 2048 + col] = (bf16)(val * qs);
        }
      }
  } else if (n0 < 2560) {          // ---- K: rope, bf16 + fp32 cache ----
    const int im = lr & 1;
#pragma unroll
    for (int mi = 0; mi < 8; mi++)
#pragma unroll
      for (int ni = 0; ni < NFR; ni++) {
        int col  = n0 + wc * (NFR * 16) + (ni << 4) + lr;
        int ck   = col - 2048;
        int i2   = (ck & 127) >> 1;
        int rowb = m0 + (wr << 7) + (mi << 4) + (lh << 2);
#pragma unroll
        for (int r = 0; r < 4; r++) {
          int row = rowb + r, s = row & 1023;
          float c = fc[(s << 6) + i2], sn = fs[(s << 6) + i2];
          float own = acc[mi][ni][r], oth = __shfl_xor(own, 1);
          float xr = im ? oth : own, xi = im ? own : oth;
          float val = im ? (xr * sn + xi * c) : (xr * c - xi * sn);
          kbf[(long)row * 512 + ck] = (bf16)val;
          kcache[(long)row * 512 + ck] = val;
        }
      }
  } else {                          // ---- V: fp32 cache + transposed bf16 ----
#pragma unroll
    for (int mi = 0; mi < 8; mi++)
#pragma unroll
      for (int ni = 0; ni < NFR; ni++) {
        int col  = n0 + wc * (NFR * 16) + (ni << 4) + lr;
        int cv   = col - 2560;
        int rowb = m0 + (wr << 7) + (mi << 4) + (lh << 2);
        bf16x4 pk;
#pragma unroll
        for (int r = 0; r < 4; r++) {
          float v = acc[mi][ni][r];
          vcache[(long)(rowb + r) * 512 + cv] = v;
          pk[r] = (bf16)v;
        }
        int b = rowb >> 10, s0 = rowb & 1023;
        *(bf16x4*)(vtb + ((long)((b << 2) + (cv >> 7)) * 128 + (cv & 127)) * 1024 + s0) = pk;
      }
  }
}

// ---------------- Flash attention (causal, GQA), double-buffered prefetch -------
__global__ __launch_bounds__(256) void attn_k(const bf16* __restrict__ qb,
                                              const bf16* __restrict__ kb,
                                              const bf16* __restrict__ vt,
                                              bf16* __restrict__ aob) {
  const int bh = blockIdx.x;
  const int qt = 15 - blockIdx.y;       // heavy-first
  const int b = bh >> 4, h = bh & 15, kv = h >> 2;
  const int t = threadIdx.x, w = t >> 6, l = t & 63, lr = l & 15, lh = l >> 4;
  __shared__ __align__(16) char Ks[2][16384];
  __shared__ __align__(16) char Vs[2][16384];
  __shared__ __align__(16) bf16 Ps[4][16][72];

  bf16x8 qfrag[4];
  {
    const int qrow = (qt << 6) + (w << 4) + lr;
    const bf16* qp = qb + ((long)(b * 1024 + qrow) << 11) + (h << 7);
#pragma unroll
    for (int kc = 0; kc < 4; kc++) qfrag[kc] = *(const bf16x8*)(qp + (kc << 5) + (lh << 3));
  }

  f32x4 acc[8];
#pragma unroll
  for (int i = 0; i < 8; i++) acc[i] = {0.f, 0.f, 0.f, 0.f};
  float m[4]  = {-1e30f, -1e30f, -1e30f, -1e30f};
  float ls[4] = {0.f, 0.f, 0.f, 0.f};

  const bf16* kg = kb + ((long)b << 19) + (kv << 7);
  const bf16* vg = vt + ((long)(b * 4 + kv) << 17);
  const int nt = qt + 1;

  auto stage = [&](int buf, int tt2) {
    const int kv0 = tt2 << 6;
#pragma unroll
    for (int pass = 0; pass < 4; pass++) {
      int c = t + (pass << 8);
      { int row = c >> 4, slot = c & 15, gs = slot ^ (row & 7);
        gload16((void*)(kg + (long)(kv0 + row) * 512 + (gs << 3)), &Ks[buf][c * 16]); }
      { int row = c >> 3, slot = c & 7,  gs = slot ^ (row & 7);
        gload16((void*)(vg + (long)row * 1024 + kv0 + (gs << 3)), &Vs[buf][c * 16]); }
    }
  };

  stage(0, 0);
  int cur = 0;

  for (int tt = 0; tt < nt; tt++) {
    __syncthreads();
    if (tt + 1 < nt) stage(cur ^ 1, tt + 1);

    f32x4 s4[4];
#pragma unroll
    for (int nf = 0; nf < 4; nf++) s4[nf] = {0.f, 0.f, 0.f, 0.f};
    __builtin_amdgcn_s_setprio(1);
#pragma unroll
    for (int nf = 0; nf < 4; nf++) {
      int key = (nf << 4) + lr;
#pragma unroll
      for (int kc = 0; kc < 4; kc++) {
        bf16x8 kf8 = *(const bf16x8*)(&Ks[cur][0] + key * 256 + (((kc << 6) + (lh << 4)) ^ ((key & 7) << 4)));
        s4[nf] = __builtin_amdgcn_mfma_f32_16x16x32_bf16(qfrag[kc], kf8, s4[nf], 0, 0, 0);
      }
    }
    __builtin_amdgcn_s_setprio(0);

    if (tt == qt) {
      const int kv0 = tt << 6;
#pragma unroll
      for (int nf = 0; nf < 4; nf++) {
        int key = kv0 + (nf << 4) + lr;
#pragma unroll
        for (int r = 0; r < 4; r++) {
          int qg = (qt << 6) + (w << 4) + (lh << 2) + r;
          if (key > qg) s4[nf][r] = -1e30f;
        }
      }
    }

    float mc[4];
#pragma unroll
    for (int r = 0; r < 4; r++)
      mc[r] = fmaxf(fmaxf(s4[0][r], s4[1][r]), fmaxf(s4[2][r], s4[3][r]));
#pragma unroll
    for (int d = 1; d < 16; d <<= 1)
#pragma unroll
      for (int r = 0; r < 4; r++) mc[r] = fmaxf(mc[r], __shfl_xor(mc[r], d));

    int grow = 0;
#pragma unroll
    for (int r = 0; r < 4; r++) grow |= (mc[r] > m[r] + 8.f) ? 1 : 0;
    if (__any(grow)) {
      f32x4 av;
#pragma unroll
      for (int r = 0; r < 4; r++) {
        float mn = fmaxf(m[r], mc[r]);
        float al = __expf(m[r] - mn);
        m[r] = mn; ls[r] *= al; av[r] = al;
      }
#pragma unroll
      for (int hf = 0; hf < 8; hf++) acc[hf] *= av;
    }

    float rs[4] = {0.f, 0.f, 0.f, 0.f};
#pragma unroll
    for (int nf = 0; nf < 4; nf++)
#pragma unroll
      for (int r = 0; r < 4; r++) {
        float p = __expf(s4[nf][r] - m[r]);
        s4[nf][r] = p;
        rs[r] += p;
      }
#pragma unroll
    for (int d = 1; d < 16; d <<= 1)
#pragma unroll
      for (int r = 0; r < 4; r++) rs[r] += __shfl_xor(rs[r], d);
#pragma unroll
    for (int r = 0; r < 4; r++) ls[r] += rs[r];

#pragma unroll
    for (int nf = 0; nf < 4; nf++)
#pragma unroll
      for (int r = 0; r < 4; r++)
        Ps[w][(lh << 2) + r][(nf << 4) + lr] = (bf16)s4[nf][r];

    __builtin_amdgcn_s_setprio(1);
#pragma unroll
    for (int kc = 0; kc < 2; kc++) {
      bf16x8 pf8 = *(const bf16x8*)((const char*)&Ps[w][lr][0] + (kc << 6) + (lh << 4));
#pragma unroll
      for (int hf = 0; hf < 8; hf++) {
        int hd = (hf << 4) + lr;
        bf16x8 vf8 = *(const bf16x8*)(&Vs[cur][0] + hd * 128 + (((kc << 6) + (lh << 4)) ^ ((hd & 7) << 4)));
        acc[hf] = __builtin_amdgcn_mfma_f32_16x16x32_bf16(pf8, vf8, acc[hf], 0, 0, 0);
      }
    }
    __builtin_amdgcn_s_setprio(0);
    cur ^= 1;
  }

  float inv[4];
#pragma unroll
  for (int r = 0; r < 4; r++) inv[r] = 1.f / ls[r];
#pragma unroll
  for (int hf = 0; hf < 8; hf++)
#pragma unroll
    for (int r = 0; r < 4; r++) {
      int qrow = (qt << 6) + (w << 4) + (lh << 2) + r;
      aob[((long)(b * 1024 + qrow) << 11) + (h << 7) + (hf << 4) + lr] = (bf16)(acc[hf][r] * inv[r]);
    }
}

// ---------------- launch -----------------------------------------
extern "C" void kernel_launch(void* const* d_in, const int* in_sizes, int n_in,
                              void* d_out, int out_size, void* d_ws, size_t ws_size,
                              hipStream_t stream) {
  (void)in_sizes; (void)n_in; (void)out_size; (void)ws_size;
  const float* x  = (const float*)d_in[0];
  const float* fc = (const float*)d_in[1];
  const float* fs = (const float*)d_in[2];
  // d_in[3] = attention_mask: pure causal, implemented directly.
  const float* wq = (const float*)d_in[4];
  const float* wk = (const float*)d_in[5];
  const float* wv = (const float*)d_in[6];
  const float* wo = (const float*)d_in[7];

  float* out    = (float*)d_out;
  float* kcache = out + 8388608;   // (4,1024,4,128)
  float* vcache = out + 10485760;  // (4,1024,4,128)

  char* ws = (char*)d_ws;
  bf16* xb    = (bf16*)(ws);                    // 16 MB
  bf16* wqkv  = (bf16*)(ws + 16777216);         // 12 MB: [wq 8 | wk 2 | wv 2]
  bf16* wob   = (bf16*)(ws + 29360128);         // 8 MB
  bf16* qbb   = (bf16*)(ws + 54525952);         // 16 MB q bf16 (roped, scaled)
  bf16* kbf   = (bf16*)(ws + 71303168);         // 4 MB k bf16 (roped)
  bf16* vtb   = (bf16*)(ws + 75497472);         // 4 MB v^T bf16
  bf16* aob   = (bf16*)(ws + 79691776);         // 16 MB attn out bf16

  cast_all<<<18432, 256, 0, stream>>>((const float4*)x, (const float4*)wq,
                                      (const float4*)wk, (const float4*)wv,
                                      (const float4*)wo,
                                      (bf16x4*)xb, (bf16x4*)wqkv,
                                      (bf16x4*)(wqkv + 4194304), (bf16x4*)wob);

  // fused QKV projection + rope + caches + V-transpose (256x256 tiles)
  gemm8<4><<<dim3(12, 16), 512, 0, stream>>>(xb, wqkv, 3072, 1, nullptr,
                                             qbb, kbf, kcache, vcache, vtb, fc, fs);

  attn_k<<<dim3(64, 16), 256, 0, stream>>>(qbb, kbf, vtb, aob);

  // output projection (256x128 tiles -> 256 blocks, full CU fill)
  gemm8<2><<<dim3(16, 16), 512, 0, stream>>>(aob, wob, 2048, 0, out,
                                             nullptr, nullptr, nullptr, nullptr, nullptr,
                                             nullptr, nullptr);
}